// Round 2
// baseline (2368.802 us; speedup 1.0000x reference)
//
#include <hip/hip_runtime.h>

#define E 256
#define H 256
#define NNODES 65535
#define DEPTH 16
#define MT 8   // nodes per block

__device__ __forceinline__ float fast_sigmoid(float x) {
    return 1.0f / (1.0f + __expf(-x));
}
__device__ __forceinline__ float fast_tanh(float x) {
    // tanh(x) = 1 - 2/(exp(2x)+1); robust at +-inf
    return 1.0f - 2.0f / (__expf(2.0f * x) + 1.0f);
}

// One level of the TreeLSTM, bottom-up. Thread t computes h-column t for MT nodes.
// hbuf = d_out[0 : N*H) (annotations), cbuf = workspace (c per node).
extern "C" __global__ void __launch_bounds__(256)
tree_level_kernel(const int* __restrict__ tokens,
                  const float* __restrict__ emb,
                  const float* __restrict__ Wx,
                  const float* __restrict__ bias,
                  const float* __restrict__ Ui,
                  const float* __restrict__ Uf,
                  const float* __restrict__ Uo,
                  const float* __restrict__ Uu,
                  float* __restrict__ hbuf,
                  float* __restrict__ cbuf,
                  float* __restrict__ rootout,
                  int lo, int m, int leaf)
{
    __shared__ float Xs[MT][E];        // embedded inputs, 8 KB
    __shared__ float HCs[MT][2 * H];   // [hL | hR] per node, 16 KB

    const int t = threadIdx.x;
    const int base = blockIdx.x * MT;

    // ---- stage X = emb[tokens[node]] (zero-fill partial tiles) ----
    for (int i = t; i < MT * (E / 4); i += 256) {
        int r = i >> 6;          // 64 float4 per row
        int c4 = i & 63;
        float4 v = make_float4(0.f, 0.f, 0.f, 0.f);
        if (base + r < m) {
            int node = lo + base + r;
            int tok = tokens[node];
            v = ((const float4*)(emb + (size_t)tok * E))[c4];
        }
        ((float4*)(Xs[r]))[c4] = v;
    }
    // ---- stage HC = [h_left | h_right] from previous level ----
    if (!leaf) {
        for (int i = t; i < MT * (2 * H / 4); i += 256) {
            int r = i >> 7;      // 128 float4 per row
            int c4 = i & 127;
            float4 v = make_float4(0.f, 0.f, 0.f, 0.f);
            if (base + r < m) {
                int node = lo + base + r;
                int child = 2 * node + 1 + (c4 >> 6);
                v = ((const float4*)(hbuf + (size_t)child * H))[c4 & 63];
            }
            ((float4*)(HCs[r]))[c4] = v;
        }
    }
    __syncthreads();

    const float bi = bias[t], bf = bias[H + t], bo = bias[2 * H + t], bu = bias[3 * H + t];
    float axi[MT], axf[MT], axo[MT], axu[MT];
    #pragma unroll
    for (int r = 0; r < MT; r++) { axi[r] = bi; axf[r] = bf; axo[r] = bo; axu[r] = bu; }

    // ---- xg = X @ Wx  (K=256, 4 gate columns per thread) ----
    for (int e0 = 0; e0 < E; e0 += 4) {
        float4 xv[MT];
        #pragma unroll
        for (int r = 0; r < MT; r++) xv[r] = *(const float4*)&Xs[r][e0];
        #pragma unroll
        for (int q = 0; q < 4; q++) {
            const float* wrow = Wx + (size_t)(e0 + q) * (4 * H);
            float w0 = wrow[t], w1 = wrow[H + t], w2 = wrow[2 * H + t], w3 = wrow[3 * H + t];
            #pragma unroll
            for (int r = 0; r < MT; r++) {
                float xvq = ((const float*)&xv[r])[q];
                axi[r] = fmaf(xvq, w0, axi[r]);
                axf[r] = fmaf(xvq, w1, axf[r]);
                axo[r] = fmaf(xvq, w2, axo[r]);
                axu[r] = fmaf(xvq, w3, axu[r]);
            }
        }
    }

    // ---- child preacts: [hL|hR](512) @ {Ui,Uo,Uu,Uf0,Uf1} ----
    // Ui[j,h,k] flat == Ucat[e=j*256+h][k]  (same for Uo,Uu,Uf[j])
    float aci[MT], aco[MT], acu[MT], acf0[MT], acf1[MT];
    #pragma unroll
    for (int r = 0; r < MT; r++) { aci[r]=0.f; aco[r]=0.f; acu[r]=0.f; acf0[r]=0.f; acf1[r]=0.f; }

    if (!leaf) {
        for (int e0 = 0; e0 < 2 * H; e0 += 2) {
            float2 hv[MT];
            #pragma unroll
            for (int r = 0; r < MT; r++) hv[r] = *(const float2*)&HCs[r][e0];
            #pragma unroll
            for (int q = 0; q < 2; q++) {
                int e = e0 + q;
                float wi  = Ui[(size_t)e * H + t];
                float wo  = Uo[(size_t)e * H + t];
                float wu  = Uu[(size_t)e * H + t];
                float wf0 = Uf[(size_t)e * H + t];
                float wf1 = Uf[2 * H * H + (size_t)e * H + t];
                #pragma unroll
                for (int r = 0; r < MT; r++) {
                    float hvq = ((const float*)&hv[r])[q];
                    aci[r]  = fmaf(hvq, wi,  aci[r]);
                    aco[r]  = fmaf(hvq, wo,  aco[r]);
                    acu[r]  = fmaf(hvq, wu,  acu[r]);
                    acf0[r] = fmaf(hvq, wf0, acf0[r]);
                    acf1[r] = fmaf(hvq, wf1, acf1[r]);
                }
            }
        }
    }

    // ---- gates + state update ----
    #pragma unroll
    for (int r = 0; r < MT; r++) {
        if (base + r < m) {
            int node = lo + base + r;
            float iv = fast_sigmoid(axi[r] + aci[r]);
            float ov = fast_sigmoid(axo[r] + aco[r]);
            float uv = fast_tanh(axu[r] + acu[r]);
            float cn;
            if (leaf) {
                cn = iv * uv;
            } else {
                float f0 = fast_sigmoid(axf[r] + acf0[r]);
                float f1 = fast_sigmoid(axf[r] + acf1[r]);
                float cl = cbuf[(size_t)(2 * node + 1) * H + t];
                float cr = cbuf[(size_t)(2 * node + 2) * H + t];
                cn = fmaf(iv, uv, fmaf(f0, cl, f1 * cr));
            }
            float hn = ov * fast_tanh(cn);
            hbuf[(size_t)node * H + t] = hn;
            cbuf[(size_t)node * H + t] = cn;
            if (rootout != nullptr && node == 0) {
                rootout[t] = hn;       // hiddens   = h[0]
                rootout[H + t] = cn;   // cell_states = c[0]
            }
        }
    }
}

extern "C" void kernel_launch(void* const* d_in, const int* in_sizes, int n_in,
                              void* d_out, int out_size, void* d_ws, size_t ws_size,
                              hipStream_t stream)
{
    const int*   tokens = (const int*)d_in[0];
    const float* emb    = (const float*)d_in[1];
    const float* Wx     = (const float*)d_in[2];
    const float* bias   = (const float*)d_in[3];
    const float* Ui     = (const float*)d_in[4];
    const float* Uf     = (const float*)d_in[5];
    const float* Uo     = (const float*)d_in[6];
    const float* Uu     = (const float*)d_in[7];

    float* out = (float*)d_out;
    float* hbuf = out;                                // annotations: [N, H]
    float* rootout = out + (size_t)NNODES * H;        // h[0] (256) + c[0] (256)
    float* cbuf = (float*)d_ws;                       // c: [N, H] = 67 MB scratch

    for (int d = DEPTH - 1; d >= 0; d--) {
        int m = 1 << d;
        int lo = m - 1;
        int grid = (m + MT - 1) / MT;
        hipLaunchKernelGGL(tree_level_kernel, dim3(grid), dim3(256), 0, stream,
                           tokens, emb, Wx, bias, Ui, Uf, Uo, Uu,
                           hbuf, cbuf, (d == 0) ? rootout : (float*)nullptr,
                           lo, m, (d == DEPTH - 1) ? 1 : 0);
    }
}

// Round 3
// 1118.653 us; speedup vs baseline: 2.1175x; 2.1175x over previous
//
#include <hip/hip_runtime.h>

#define E 256
#define H 256
#define NNODES 65535
#define DEPTH 16
#define MT 8   // nodes per block (fallback fp32 kernel)

typedef __attribute__((ext_vector_type(8))) short bf16x8;
typedef __attribute__((ext_vector_type(4))) float f32x4;

__device__ __forceinline__ float fast_sigmoid(float x) {
    return 1.0f / (1.0f + __expf(-x));
}
__device__ __forceinline__ float fast_tanh(float x) {
    return 1.0f - 2.0f / (__expf(2.0f * x) + 1.0f);
}
__device__ __forceinline__ ushort f2bf(float v) {
    union { float f; unsigned u; } x; x.f = v;
    unsigned r = (x.u + 0x7FFFu + ((x.u >> 16) & 1u)) >> 16;
    return (ushort)r;
}
__device__ __forceinline__ float bf2f(ushort h) {
    union { unsigned u; float f; } x; x.u = ((unsigned)h) << 16;
    return x.f;
}

// ============================================================================
// Pack B (768 x 1280 logical) into MFMA-fragment-ready bf16 hi/lo arrays.
// Logical B rows: 0..255 = x (Wx), 256..511 = hL (U*[0]), 512..767 = hR (U*[1]).
// Logical B cols grouped: ctp = (nb*4+w)*5+g; col = g*256 + nb*64 + w*16 + c,
// g: 0=i 1=o 2=u 3=f(child0) 4=f(child1).  Frag slot for (kt,ctp,lane l, j):
// value B[kt*32 + (l>>4)*8 + j][...c=(l&15)], stored at ((kt*80+ctp)*64+l)*8+j.
// ============================================================================
__global__ __launch_bounds__(256) void pack_B(const float* __restrict__ Wx,
                                              const float* __restrict__ Ui,
                                              const float* __restrict__ Uf,
                                              const float* __restrict__ Uo,
                                              const float* __restrict__ Uu,
                                              ushort* __restrict__ Bh,
                                              ushort* __restrict__ Bl)
{
    int tile = blockIdx.x * 4 + (threadIdx.x >> 6);   // 0..1919 = 24 kt x 80 ctp
    int l = threadIdx.x & 63;
    int kt = tile / 80;
    int ctp = tile % 80;
    int g = ctp % 5, w = (ctp / 5) & 3, nb = ctp / 20;
    int q = nb * 64 + w * 16 + (l & 15);
    size_t base = ((size_t)tile * 64 + l) * 8;
    #pragma unroll
    for (int j = 0; j < 8; j++) {
        int k = kt * 32 + ((l >> 4) * 8) + j;
        float v;
        if (k < 256) {
            // Wx gate quarters (reference order i,f,o,u): i->q, o->768?? no:
            // i: cols 0..255, f: 256..511, o: 512..767, u: 768..1023
            int gc = (g == 0) ? q : (g == 1) ? (512 + q) : (g == 2) ? (768 + q) : (256 + q);
            v = Wx[(size_t)k * 1024 + gc];
        } else {
            int side = (k < 512) ? 0 : 1;            // hL / hR
            int e = k - 256 - side * 256;
            size_t off = (size_t)e * 256 + q;
            if (g == 0)      v = Ui[(size_t)side * 65536 + off];
            else if (g == 1) v = Uo[(size_t)side * 65536 + off];
            else if (g == 2) v = Uu[(size_t)side * 65536 + off];
            else {
                int j2 = g - 3;                      // forget gate of child j2
                v = Uf[(size_t)(j2 * 2 + side) * 65536 + off];
            }
        }
        ushort hi = f2bf(v);
        float lo = v - bf2f(hi);
        Bh[base + j] = hi;
        Bl[base + j] = f2bf(lo);
    }
}

// ============================================================================
// One tree level, fused GEMM (bf16x3) + LSTM epilogue.
// A = [X | hL | hR] per node (K = 768; leaves: K = 256), N = 1280 (5 gates).
// Block: 64 (=MTC*16) nodes x 320 cols (one q-block nb of 64 q x 5 gates).
// Wave w handles q-subtile w: all MTC m-tiles x 5 gate-tiles, acc[MTC][5].
// ============================================================================
template <int MTC, bool LEAF>
__global__ __launch_bounds__(256, 2) void tree_level_mfma(
    const int* __restrict__ tokens, const float* __restrict__ emb,
    const float* __restrict__ bias,
    const ushort* __restrict__ Bh, const ushort* __restrict__ Bl,
    float* __restrict__ hbuf, float* __restrict__ cbuf,
    float* __restrict__ rootout, int lo, int m)
{
    constexpr int ROWS = MTC * 16;
    constexpr int KTOT = LEAF ? 256 : 768;
    constexpr int NG = LEAF ? 3 : 5;

    __shared__ __attribute__((aligned(16))) ushort Ahs[ROWS * 128];
    __shared__ __attribute__((aligned(16))) ushort Als[ROWS * 128];

    const int t = threadIdx.x;
    const int l = t & 63;
    const int w = t >> 6;
    const int base = blockIdx.x * ROWS;
    const int nb = blockIdx.y;

    f32x4 acc[MTC][NG];
    #pragma unroll
    for (int mt = 0; mt < MTC; mt++)
        #pragma unroll
        for (int g = 0; g < NG; g++)
            acc[mt][g] = (f32x4){0.f, 0.f, 0.f, 0.f};

    for (int kc = 0; kc < KTOT; kc += 128) {
        __syncthreads();   // protect LDS from previous chunk's readers
        // ---- stage A chunk [ROWS][128] fp32 -> bf16 hi/lo, XOR-swizzled ----
        #pragma unroll
        for (int it = 0; it < MTC * 2; it++) {
            int f = it * 256 + t;          // f4 index: ROWS*32 total
            int row = f >> 5;
            int c4 = f & 31;
            float4 v = make_float4(0.f, 0.f, 0.f, 0.f);
            if (base + row < m) {
                int node = lo + base + row;
                int rowoff = (kc & 255) + c4 * 4;
                if (LEAF || kc < 256) {
                    int tok = tokens[node];
                    v = *(const float4*)(emb + (size_t)tok * 256 + rowoff);
                } else {
                    int child = 2 * node + ((kc < 512) ? 1 : 2);
                    v = *(const float4*)(hbuf + (size_t)child * 256 + rowoff);
                }
            }
            ushort4 hv, lv;
            hv.x = f2bf(v.x); lv.x = f2bf(v.x - bf2f(hv.x));
            hv.y = f2bf(v.y); lv.y = f2bf(v.y - bf2f(hv.y));
            hv.z = f2bf(v.z); lv.z = f2bf(v.z - bf2f(hv.z));
            hv.w = f2bf(v.w); lv.w = f2bf(v.w - bf2f(hv.w));
            int byteoff = row * 256 + ((c4 * 8) ^ ((row & 7) << 4));
            *reinterpret_cast<ushort4*>(reinterpret_cast<char*>(Ahs) + byteoff) = hv;
            *reinterpret_cast<ushort4*>(reinterpret_cast<char*>(Als) + byteoff) = lv;
        }
        __syncthreads();

        // ---- 4 MFMA K-steps over this 128-K chunk ----
        #pragma unroll
        for (int ks = 0; ks < 4; ks++) {
            bf16x8 Ah[MTC], Al[MTC];
            #pragma unroll
            for (int mt = 0; mt < MTC; mt++) {
                int row = mt * 16 + (l & 15);
                int kb = (ks * 64 + (l >> 4) * 16) ^ ((row & 7) << 4);
                const char* p = reinterpret_cast<const char*>(Ahs) + row * 256 + kb;
                const char* pl = reinterpret_cast<const char*>(Als) + row * 256 + kb;
                Ah[mt] = *reinterpret_cast<const bf16x8*>(p);
                Al[mt] = *reinterpret_cast<const bf16x8*>(pl);
            }
            int kt = (kc >> 5) + ks;
            #pragma unroll
            for (int g = 0; g < NG; g++) {
                int ctp = (nb * 4 + w) * 5 + g;
                size_t boff = (((size_t)kt * 80 + ctp) * 64 + l) * 8;
                bf16x8 bh = *reinterpret_cast<const bf16x8*>(Bh + boff);
                bf16x8 bl = *reinterpret_cast<const bf16x8*>(Bl + boff);
                #pragma unroll
                for (int mt = 0; mt < MTC; mt++) {
                    acc[mt][g] = __builtin_amdgcn_mfma_f32_16x16x32_bf16(Ah[mt], bh, acc[mt][g], 0, 0, 0);
                    acc[mt][g] = __builtin_amdgcn_mfma_f32_16x16x32_bf16(Ah[mt], bl, acc[mt][g], 0, 0, 0);
                    acc[mt][g] = __builtin_amdgcn_mfma_f32_16x16x32_bf16(Al[mt], bh, acc[mt][g], 0, 0, 0);
                }
            }
        }
    }

    // ---- LSTM epilogue: C/D layout col=lane&15, row=(lane>>4)*4+reg ----
    int q = nb * 64 + w * 16 + (l & 15);
    float bi = bias[q], bff = bias[256 + q], bo = bias[512 + q], bu = bias[768 + q];
    #pragma unroll
    for (int mt = 0; mt < MTC; mt++) {
        #pragma unroll
        for (int r = 0; r < 4; r++) {
            int row = mt * 16 + (l >> 4) * 4 + r;
            if (base + row < m) {
                int node = lo + base + row;
                float iv = fast_sigmoid(acc[mt][0][r] + bi);
                float ov = fast_sigmoid(acc[mt][1][r] + bo);
                float uv = fast_tanh(acc[mt][2][r] + bu);
                float cn;
                if constexpr (LEAF) {
                    cn = iv * uv;
                } else {
                    float f0 = fast_sigmoid(acc[mt][3][r] + bff);
                    float f1 = fast_sigmoid(acc[mt][4][r] + bff);
                    float cl = cbuf[(size_t)(2 * node + 1) * 256 + q];
                    float cr = cbuf[(size_t)(2 * node + 2) * 256 + q];
                    cn = fmaf(iv, uv, fmaf(f0, cl, f1 * cr));
                }
                float hn = ov * fast_tanh(cn);
                hbuf[(size_t)node * 256 + q] = hn;
                cbuf[(size_t)node * 256 + q] = cn;
                if constexpr (!LEAF) {
                    if (rootout != nullptr && node == 0) {
                        rootout[q] = hn;
                        rootout[256 + q] = cn;
                    }
                }
            }
        }
    }
}

// ============================================================================
// Fallback fp32 path (round-2 kernel, known-correct) if ws too small.
// ============================================================================
extern "C" __global__ void __launch_bounds__(256)
tree_level_kernel(const int* __restrict__ tokens,
                  const float* __restrict__ emb,
                  const float* __restrict__ Wx,
                  const float* __restrict__ bias,
                  const float* __restrict__ Ui,
                  const float* __restrict__ Uf,
                  const float* __restrict__ Uo,
                  const float* __restrict__ Uu,
                  float* __restrict__ hbuf,
                  float* __restrict__ cbuf,
                  float* __restrict__ rootout,
                  int lo, int m, int leaf)
{
    __shared__ float Xs[MT][E];
    __shared__ float HCs[MT][2 * H];
    const int t = threadIdx.x;
    const int base = blockIdx.x * MT;
    for (int i = t; i < MT * (E / 4); i += 256) {
        int r = i >> 6, c4 = i & 63;
        float4 v = make_float4(0.f, 0.f, 0.f, 0.f);
        if (base + r < m) {
            int node = lo + base + r;
            v = ((const float4*)(emb + (size_t)tokens[node] * E))[c4];
        }
        ((float4*)(Xs[r]))[c4] = v;
    }
    if (!leaf) {
        for (int i = t; i < MT * (2 * H / 4); i += 256) {
            int r = i >> 7, c4 = i & 127;
            float4 v = make_float4(0.f, 0.f, 0.f, 0.f);
            if (base + r < m) {
                int node = lo + base + r;
                int child = 2 * node + 1 + (c4 >> 6);
                v = ((const float4*)(hbuf + (size_t)child * H))[c4 & 63];
            }
            ((float4*)(HCs[r]))[c4] = v;
        }
    }
    __syncthreads();
    const float bi = bias[t], bf = bias[H + t], bo = bias[2 * H + t], bu = bias[3 * H + t];
    float axi[MT], axf[MT], axo[MT], axu[MT];
    #pragma unroll
    for (int r = 0; r < MT; r++) { axi[r] = bi; axf[r] = bf; axo[r] = bo; axu[r] = bu; }
    for (int e0 = 0; e0 < E; e0 += 4) {
        float4 xv[MT];
        #pragma unroll
        for (int r = 0; r < MT; r++) xv[r] = *(const float4*)&Xs[r][e0];
        #pragma unroll
        for (int q = 0; q < 4; q++) {
            const float* wrow = Wx + (size_t)(e0 + q) * (4 * H);
            float w0 = wrow[t], w1 = wrow[H + t], w2 = wrow[2 * H + t], w3 = wrow[3 * H + t];
            #pragma unroll
            for (int r = 0; r < MT; r++) {
                float xvq = ((const float*)&xv[r])[q];
                axi[r] = fmaf(xvq, w0, axi[r]);
                axf[r] = fmaf(xvq, w1, axf[r]);
                axo[r] = fmaf(xvq, w2, axo[r]);
                axu[r] = fmaf(xvq, w3, axu[r]);
            }
        }
    }
    float aci[MT], aco[MT], acu[MT], acf0[MT], acf1[MT];
    #pragma unroll
    for (int r = 0; r < MT; r++) { aci[r]=0.f; aco[r]=0.f; acu[r]=0.f; acf0[r]=0.f; acf1[r]=0.f; }
    if (!leaf) {
        for (int e0 = 0; e0 < 2 * H; e0 += 2) {
            float2 hv[MT];
            #pragma unroll
            for (int r = 0; r < MT; r++) hv[r] = *(const float2*)&HCs[r][e0];
            #pragma unroll
            for (int q = 0; q < 2; q++) {
                int e = e0 + q;
                float wi  = Ui[(size_t)e * H + t];
                float wo  = Uo[(size_t)e * H + t];
                float wu  = Uu[(size_t)e * H + t];
                float wf0 = Uf[(size_t)e * H + t];
                float wf1 = Uf[2 * H * H + (size_t)e * H + t];
                #pragma unroll
                for (int r = 0; r < MT; r++) {
                    float hvq = ((const float*)&hv[r])[q];
                    aci[r]  = fmaf(hvq, wi,  aci[r]);
                    aco[r]  = fmaf(hvq, wo,  aco[r]);
                    acu[r]  = fmaf(hvq, wu,  acu[r]);
                    acf0[r] = fmaf(hvq, wf0, acf0[r]);
                    acf1[r] = fmaf(hvq, wf1, acf1[r]);
                }
            }
        }
    }
    #pragma unroll
    for (int r = 0; r < MT; r++) {
        if (base + r < m) {
            int node = lo + base + r;
            float iv = fast_sigmoid(axi[r] + aci[r]);
            float ov = fast_sigmoid(axo[r] + aco[r]);
            float uv = fast_tanh(axu[r] + acu[r]);
            float cn;
            if (leaf) cn = iv * uv;
            else {
                float f0 = fast_sigmoid(axf[r] + acf0[r]);
                float f1 = fast_sigmoid(axf[r] + acf1[r]);
                float cl = cbuf[(size_t)(2 * node + 1) * H + t];
                float cr = cbuf[(size_t)(2 * node + 2) * H + t];
                cn = fmaf(iv, uv, fmaf(f0, cl, f1 * cr));
            }
            float hn = ov * fast_tanh(cn);
            hbuf[(size_t)node * H + t] = hn;
            cbuf[(size_t)node * H + t] = cn;
            if (rootout != nullptr && node == 0) { rootout[t] = hn; rootout[H + t] = cn; }
        }
    }
}

extern "C" void kernel_launch(void* const* d_in, const int* in_sizes, int n_in,
                              void* d_out, int out_size, void* d_ws, size_t ws_size,
                              hipStream_t stream)
{
    const int*   tokens = (const int*)d_in[0];
    const float* emb    = (const float*)d_in[1];
    const float* Wx     = (const float*)d_in[2];
    const float* bias   = (const float*)d_in[3];
    const float* Ui     = (const float*)d_in[4];
    const float* Uf     = (const float*)d_in[5];
    const float* Uo     = (const float*)d_in[6];
    const float* Uu     = (const float*)d_in[7];

    float* out = (float*)d_out;
    float* hbuf = out;                              // annotations [N, H]
    float* rootout = out + (size_t)NNODES * H;      // h[0], c[0]

    const size_t cbytes = (size_t)NNODES * H * sizeof(float);      // 67,107,840
    const size_t bElems = 768 * 1280;                               // packed B
    const size_t need = cbytes + 2 * bElems * sizeof(ushort);       // ~71.0 MB

    float* cbuf = (float*)d_ws;

    if (ws_size >= need) {
        ushort* Bh = (ushort*)((char*)d_ws + cbytes);
        ushort* Bl = Bh + bElems;
        pack_B<<<480, 256, 0, stream>>>(Wx, Ui, Uf, Uo, Uu, Bh, Bl);
        for (int d = DEPTH - 1; d >= 0; d--) {
            int m = 1 << d;
            int lo = m - 1;
            float* ro = (d == 0) ? rootout : nullptr;
            if (d == DEPTH - 1) {
                tree_level_mfma<4, true><<<dim3(m / 64, 4), 256, 0, stream>>>(
                    tokens, emb, bias, Bh, Bl, hbuf, cbuf, nullptr, lo, m);
            } else if (m >= 64) {
                tree_level_mfma<4, false><<<dim3(m / 64, 4), 256, 0, stream>>>(
                    tokens, emb, bias, Bh, Bl, hbuf, cbuf, ro, lo, m);
            } else if (m == 32) {
                tree_level_mfma<2, false><<<dim3(1, 4), 256, 0, stream>>>(
                    tokens, emb, bias, Bh, Bl, hbuf, cbuf, ro, lo, m);
            } else {
                tree_level_mfma<1, false><<<dim3(1, 4), 256, 0, stream>>>(
                    tokens, emb, bias, Bh, Bl, hbuf, cbuf, ro, lo, m);
            }
        }
    } else {
        // fallback: fp32 VALU path
        for (int d = DEPTH - 1; d >= 0; d--) {
            int m = 1 << d;
            int lo = m - 1;
            int grid = (m + MT - 1) / MT;
            tree_level_kernel<<<grid, 256, 0, stream>>>(
                tokens, emb, Wx, bias, Ui, Uf, Uo, Uu,
                hbuf, cbuf, (d == 0) ? rootout : nullptr,
                lo, m, (d == DEPTH - 1) ? 1 : 0);
        }
    }
}

// Round 5
// 634.875 us; speedup vs baseline: 3.7311x; 1.7620x over previous
//
#include <hip/hip_runtime.h>

#define E 256
#define H 256
#define NNODES 65535
#define DEPTH 16
#define MT 8   // nodes per block (fallback fp32 kernel)

typedef __attribute__((ext_vector_type(8))) short bf16x8;
typedef __attribute__((ext_vector_type(4))) float f32x4;

__device__ __forceinline__ float fast_sigmoid(float x) {
    return 1.0f / (1.0f + __expf(-x));
}
__device__ __forceinline__ float fast_tanh(float x) {
    return 1.0f - 2.0f / (__expf(2.0f * x) + 1.0f);
}
__device__ __forceinline__ ushort f2bf(float v) {
    union { float f; unsigned u; } x; x.f = v;
    unsigned r = (x.u + 0x7FFFu + ((x.u >> 16) & 1u)) >> 16;
    return (ushort)r;
}
__device__ __forceinline__ float bf2f(ushort h) {
    union { unsigned u; float f; } x; x.u = ((unsigned)h) << 16;
    return x.f;
}

// ============================================================================
// Pack B (768 x 1280 logical) into MFMA-fragment-ready bf16 (hi only; 2-term
// scheme keeps A at ~f32 precision via Ah+Al, B rounds to bf16).
// Logical B rows: 0..255 = x (Wx), 256..511 = hL (U*[0]), 512..767 = hR (U*[1]).
// ctp = (nb*4+w)*5+g; col = g*256 + nb*64 + w*16 + c, g: 0=i 1=o 2=u 3=f0 4=f1.
// Frag slot for (kt,ctp,lane l,j): B[kt*32+(l>>4)*8+j][col c=(l&15)]
// stored at ((kt*80+ctp)*64+l)*8+j.
// ============================================================================
__global__ __launch_bounds__(256) void pack_B(const float* __restrict__ Wx,
                                              const float* __restrict__ Ui,
                                              const float* __restrict__ Uf,
                                              const float* __restrict__ Uo,
                                              const float* __restrict__ Uu,
                                              ushort* __restrict__ Bh)
{
    int tile = blockIdx.x * 4 + (threadIdx.x >> 6);   // 0..1919 = 24 kt x 80 ctp
    int l = threadIdx.x & 63;
    int kt = tile / 80;
    int ctp = tile % 80;
    int g = ctp % 5, w = (ctp / 5) & 3, nb = ctp / 20;
    int q = nb * 64 + w * 16 + (l & 15);
    size_t base = ((size_t)tile * 64 + l) * 8;
    #pragma unroll
    for (int j = 0; j < 8; j++) {
        int k = kt * 32 + ((l >> 4) * 8) + j;
        float v;
        if (k < 256) {
            // Wx gate order in reference: i,f,o,u
            int gc = (g == 0) ? q : (g == 1) ? (512 + q) : (g == 2) ? (768 + q) : (256 + q);
            v = Wx[(size_t)k * 1024 + gc];
        } else {
            int side = (k < 512) ? 0 : 1;            // hL / hR
            int e = k - 256 - side * 256;
            size_t off = (size_t)e * 256 + q;
            if (g == 0)      v = Ui[(size_t)side * 65536 + off];
            else if (g == 1) v = Uo[(size_t)side * 65536 + off];
            else if (g == 2) v = Uu[(size_t)side * 65536 + off];
            else {
                int j2 = g - 3;                      // forget gate of child j2
                v = Uf[(size_t)(j2 * 2 + side) * 65536 + off];
            }
        }
        Bh[base + j] = f2bf(v);
    }
}

// ============================================================================
// One tree level, fused GEMM (2-term: Ah*Bh + Al*Bh) + LSTM epilogue.
// A = [X | hL | hR] per node (K = 768; leaves: K = 256), N = 1280 (5 gates).
// Block: MTC*16 nodes x 320 cols (one q-block nb: 64 q x 5 gates).
// Wave w: q-subtile w, all MTC m-tiles x NG gate-tiles, acc[MTC][NG].
// ============================================================================
template <int MTC, bool LEAF>
__global__ __launch_bounds__(256, 2) void tree_level_mfma(
    const int* __restrict__ tokens, const float* __restrict__ emb,
    const float* __restrict__ bias,
    const ushort* __restrict__ Bh,
    float* __restrict__ hbuf, float* __restrict__ cbuf,
    float* __restrict__ rootout, int lo, int m)
{
    constexpr int ROWS = MTC * 16;
    constexpr int KTOT = LEAF ? 256 : 768;
    constexpr int NG = LEAF ? 3 : 5;

    __shared__ __attribute__((aligned(16))) ushort Ahs[ROWS * 128];
    __shared__ __attribute__((aligned(16))) ushort Als[ROWS * 128];

    const int t = threadIdx.x;
    const int l = t & 63;
    const int w = t >> 6;
    const int base = blockIdx.x * ROWS;
    const int nb = blockIdx.y;

    f32x4 acc[MTC][NG];
    #pragma unroll
    for (int mt = 0; mt < MTC; mt++)
        #pragma unroll
        for (int g = 0; g < NG; g++)
            acc[mt][g] = (f32x4){0.f, 0.f, 0.f, 0.f};

    for (int kc = 0; kc < KTOT; kc += 128) {
        __syncthreads();   // protect LDS from previous chunk's readers
        // ---- stage A chunk [ROWS][128] fp32 -> bf16 hi/lo, XOR-swizzled ----
        #pragma unroll
        for (int it = 0; it < MTC * 2; it++) {
            int f = it * 256 + t;          // f4 index: ROWS*32 total
            int row = f >> 5;
            int c4 = f & 31;
            float4 v = make_float4(0.f, 0.f, 0.f, 0.f);
            if (base + row < m) {
                int node = lo + base + row;
                int rowoff = (kc & 255) + c4 * 4;
                if (LEAF || kc < 256) {
                    int tok = tokens[node];
                    v = *(const float4*)(emb + (size_t)tok * 256 + rowoff);
                } else {
                    int child = 2 * node + ((kc < 512) ? 1 : 2);
                    v = *(const float4*)(hbuf + (size_t)child * 256 + rowoff);
                }
            }
            ushort4 hv, lv;
            hv.x = f2bf(v.x); lv.x = f2bf(v.x - bf2f(hv.x));
            hv.y = f2bf(v.y); lv.y = f2bf(v.y - bf2f(hv.y));
            hv.z = f2bf(v.z); lv.z = f2bf(v.z - bf2f(hv.z));
            hv.w = f2bf(v.w); lv.w = f2bf(v.w - bf2f(hv.w));
            int byteoff = row * 256 + ((c4 * 8) ^ ((row & 7) << 4));
            *reinterpret_cast<ushort4*>(reinterpret_cast<char*>(Ahs) + byteoff) = hv;
            *reinterpret_cast<ushort4*>(reinterpret_cast<char*>(Als) + byteoff) = lv;
        }
        __syncthreads();

        // ---- 4 MFMA K-steps over this 128-K chunk ----
        #pragma unroll
        for (int ks = 0; ks < 4; ks++) {
            bf16x8 Ah[MTC], Al[MTC];
            #pragma unroll
            for (int mt = 0; mt < MTC; mt++) {
                int row = mt * 16 + (l & 15);
                int kb = (ks * 64 + (l >> 4) * 16) ^ ((row & 7) << 4);
                const char* p = reinterpret_cast<const char*>(Ahs) + row * 256 + kb;
                const char* pl = reinterpret_cast<const char*>(Als) + row * 256 + kb;
                Ah[mt] = *reinterpret_cast<const bf16x8*>(p);
                Al[mt] = *reinterpret_cast<const bf16x8*>(pl);
            }
            int kt = (kc >> 5) + ks;
            #pragma unroll
            for (int g = 0; g < NG; g++) {
                int ctp = (nb * 4 + w) * 5 + g;
                size_t boff = (((size_t)kt * 80 + ctp) * 64 + l) * 8;
                bf16x8 bh = *reinterpret_cast<const bf16x8*>(Bh + boff);
                #pragma unroll
                for (int mt = 0; mt < MTC; mt++) {
                    acc[mt][g] = __builtin_amdgcn_mfma_f32_16x16x32_bf16(Ah[mt], bh, acc[mt][g], 0, 0, 0);
                    acc[mt][g] = __builtin_amdgcn_mfma_f32_16x16x32_bf16(Al[mt], bh, acc[mt][g], 0, 0, 0);
                }
            }
        }
    }

    // ---- LSTM epilogue: C/D layout col=lane&15, row=(lane>>4)*4+reg ----
    int q = nb * 64 + w * 16 + (l & 15);
    float bi = bias[q], bff = bias[256 + q], bo = bias[512 + q], bu = bias[768 + q];
    #pragma unroll
    for (int mt = 0; mt < MTC; mt++) {
        #pragma unroll
        for (int r = 0; r < 4; r++) {
            int row = mt * 16 + (l >> 4) * 4 + r;
            if (base + row < m) {
                int node = lo + base + row;
                float iv = fast_sigmoid(acc[mt][0][r] + bi);
                float ov = fast_sigmoid(acc[mt][1][r] + bo);
                float uv = fast_tanh(acc[mt][2][r] + bu);
                float cn;
                if constexpr (LEAF) {
                    cn = iv * uv;
                } else {
                    float f0 = fast_sigmoid(acc[mt][3][r] + bff);
                    float f1 = fast_sigmoid(acc[mt][4][r] + bff);
                    float cl = cbuf[(size_t)(2 * node + 1) * 256 + q];
                    float cr = cbuf[(size_t)(2 * node + 2) * 256 + q];
                    cn = fmaf(iv, uv, fmaf(f0, cl, f1 * cr));
                }
                float hn = ov * fast_tanh(cn);
                hbuf[(size_t)node * 256 + q] = hn;
                cbuf[(size_t)node * 256 + q] = cn;
                if constexpr (!LEAF) {
                    if (rootout != nullptr && node == 0) {
                        rootout[q] = hn;
                        rootout[256 + q] = cn;
                    }
                }
            }
        }
    }
}

// ============================================================================
// Fallback fp32 path (round-2 kernel, known-correct) if ws too small.
// ============================================================================
extern "C" __global__ void __launch_bounds__(256)
tree_level_kernel(const int* __restrict__ tokens,
                  const float* __restrict__ emb,
                  const float* __restrict__ Wx,
                  const float* __restrict__ bias,
                  const float* __restrict__ Ui,
                  const float* __restrict__ Uf,
                  const float* __restrict__ Uo,
                  const float* __restrict__ Uu,
                  float* __restrict__ hbuf,
                  float* __restrict__ cbuf,
                  float* __restrict__ rootout,
                  int lo, int m, int leaf)
{
    __shared__ float Xs[MT][E];
    __shared__ float HCs[MT][2 * H];
    const int t = threadIdx.x;
    const int base = blockIdx.x * MT;
    for (int i = t; i < MT * (E / 4); i += 256) {
        int r = i >> 6, c4 = i & 63;
        float4 v = make_float4(0.f, 0.f, 0.f, 0.f);
        if (base + r < m) {
            int node = lo + base + r;
            v = ((const float4*)(emb + (size_t)tokens[node] * E))[c4];
        }
        ((float4*)(Xs[r]))[c4] = v;
    }
    if (!leaf) {
        for (int i = t; i < MT * (2 * H / 4); i += 256) {
            int r = i >> 7, c4 = i & 127;
            float4 v = make_float4(0.f, 0.f, 0.f, 0.f);
            if (base + r < m) {
                int node = lo + base + r;
                int child = 2 * node + 1 + (c4 >> 6);
                v = ((const float4*)(hbuf + (size_t)child * H))[c4 & 63];
            }
            ((float4*)(HCs[r]))[c4] = v;
        }
    }
    __syncthreads();
    const float bi = bias[t], bf = bias[H + t], bo = bias[2 * H + t], bu = bias[3 * H + t];
    float axi[MT], axf[MT], axo[MT], axu[MT];
    #pragma unroll
    for (int r = 0; r < MT; r++) { axi[r] = bi; axf[r] = bf; axo[r] = bo; axu[r] = bu; }
    for (int e0 = 0; e0 < E; e0 += 4) {
        float4 xv[MT];
        #pragma unroll
        for (int r = 0; r < MT; r++) xv[r] = *(const float4*)&Xs[r][e0];
        #pragma unroll
        for (int q = 0; q < 4; q++) {
            const float* wrow = Wx + (size_t)(e0 + q) * (4 * H);
            float w0 = wrow[t], w1 = wrow[H + t], w2 = wrow[2 * H + t], w3 = wrow[3 * H + t];
            #pragma unroll
            for (int r = 0; r < MT; r++) {
                float xvq = ((const float*)&xv[r])[q];
                axi[r] = fmaf(xvq, w0, axi[r]);
                axf[r] = fmaf(xvq, w1, axf[r]);
                axo[r] = fmaf(xvq, w2, axo[r]);
                axu[r] = fmaf(xvq, w3, axu[r]);
            }
        }
    }
    float aci[MT], aco[MT], acu[MT], acf0[MT], acf1[MT];
    #pragma unroll
    for (int r = 0; r < MT; r++) { aci[r]=0.f; aco[r]=0.f; acu[r]=0.f; acf0[r]=0.f; acf1[r]=0.f; }
    if (!leaf) {
        for (int e0 = 0; e0 < 2 * H; e0 += 2) {
            float2 hv[MT];
            #pragma unroll
            for (int r = 0; r < MT; r++) hv[r] = *(const float2*)&HCs[r][e0];
            #pragma unroll
            for (int q = 0; q < 2; q++) {
                int e = e0 + q;
                float wi  = Ui[(size_t)e * H + t];
                float wo  = Uo[(size_t)e * H + t];
                float wu  = Uu[(size_t)e * H + t];
                float wf0 = Uf[(size_t)e * H + t];
                float wf1 = Uf[2 * H * H + (size_t)e * H + t];
                #pragma unroll
                for (int r = 0; r < MT; r++) {
                    float hvq = ((const float*)&hv[r])[q];
                    aci[r]  = fmaf(hvq, wi,  aci[r]);
                    aco[r]  = fmaf(hvq, wo,  aco[r]);
                    acu[r]  = fmaf(hvq, wu,  acu[r]);
                    acf0[r] = fmaf(hvq, wf0, acf0[r]);
                    acf1[r] = fmaf(hvq, wf1, acf1[r]);
                }
            }
        }
    }
    #pragma unroll
    for (int r = 0; r < MT; r++) {
        if (base + r < m) {
            int node = lo + base + r;
            float iv = fast_sigmoid(axi[r] + aci[r]);
            float ov = fast_sigmoid(axo[r] + aco[r]);
            float uv = fast_tanh(axu[r] + acu[r]);
            float cn;
            if (leaf) cn = iv * uv;
            else {
                float f0 = fast_sigmoid(axf[r] + acf0[r]);
                float f1 = fast_sigmoid(axf[r] + acf1[r]);
                float cl = cbuf[(size_t)(2 * node + 1) * H + t];
                float cr = cbuf[(size_t)(2 * node + 2) * H + t];
                cn = fmaf(iv, uv, fmaf(f0, cl, f1 * cr));
            }
            float hn = ov * fast_tanh(cn);
            hbuf[(size_t)node * H + t] = hn;
            cbuf[(size_t)node * H + t] = cn;
            if (rootout != nullptr && node == 0) { rootout[t] = hn; rootout[H + t] = cn; }
        }
    }
}

extern "C" void kernel_launch(void* const* d_in, const int* in_sizes, int n_in,
                              void* d_out, int out_size, void* d_ws, size_t ws_size,
                              hipStream_t stream)
{
    const int*   tokens = (const int*)d_in[0];
    const float* emb    = (const float*)d_in[1];
    const float* Wx     = (const float*)d_in[2];
    const float* bias   = (const float*)d_in[3];
    const float* Ui     = (const float*)d_in[4];
    const float* Uf     = (const float*)d_in[5];
    const float* Uo     = (const float*)d_in[6];
    const float* Uu     = (const float*)d_in[7];

    float* out = (float*)d_out;
    float* hbuf = out;                              // annotations [N, H]
    float* rootout = out + (size_t)NNODES * H;      // h[0], c[0]

    const size_t cbytes = (size_t)NNODES * H * sizeof(float);      // 67,107,840
    const size_t bElems = 768 * 1280;                               // packed B
    const size_t need = cbytes + bElems * sizeof(ushort);           // ~69 MB

    float* cbuf = (float*)d_ws;

    if (ws_size >= need) {
        ushort* Bh = (ushort*)((char*)d_ws + cbytes);
        pack_B<<<480, 256, 0, stream>>>(Wx, Ui, Uf, Uo, Uu, Bh);
        for (int d = DEPTH - 1; d >= 0; d--) {
            int m = 1 << d;
            int lo = m - 1;
            float* ro = (d == 0) ? rootout : nullptr;
            if (d == DEPTH - 1) {
                // leaf level: K=256, 3 gates, MTC=4
                tree_level_mfma<4, true><<<dim3(m / 64, 4), 256, 0, stream>>>(
                    tokens, emb, bias, Bh, hbuf, cbuf, nullptr, lo, m);
            } else if (m >= 8192) {
                // big internal levels: throughput config (>=512 blocks of MTC4)
                tree_level_mfma<4, false><<<dim3(m / 64, 4), 256, 0, stream>>>(
                    tokens, emb, bias, Bh, hbuf, cbuf, ro, lo, m);
            } else if (m >= 4096) {
                // 512 blocks of MTC2: full GPU, halved per-block latency
                tree_level_mfma<2, false><<<dim3(m / 32, 4), 256, 0, stream>>>(
                    tokens, emb, bias, Bh, hbuf, cbuf, ro, lo, m);
            } else {
                // tail: latency-bound — minimal per-block serial work (MTC1)
                int gx = (m + 15) / 16;
                tree_level_mfma<1, false><<<dim3(gx, 4), 256, 0, stream>>>(
                    tokens, emb, bias, Bh, hbuf, cbuf, ro, lo, m);
            }
        }
    } else {
        // fallback: fp32 VALU path
        for (int d = DEPTH - 1; d >= 0; d--) {
            int m = 1 << d;
            int lo = m - 1;
            int grid = (m + MT - 1) / MT;
            tree_level_kernel<<<grid, 256, 0, stream>>>(
                tokens, emb, Wx, bias, Ui, Uf, Uo, Uu,
                hbuf, cbuf, (d == 0) ? rootout : nullptr,
                lo, m, (d == DEPTH - 1) ? 1 : 0);
        }
    }
}

// Round 6
// 538.666 us; speedup vs baseline: 4.3975x; 1.1786x over previous
//
#include <hip/hip_runtime.h>

#define E 256
#define H 256
#define NNODES 65535
#define DEPTH 16
#define MT 8   // nodes per block (fallback fp32 kernel)

typedef __attribute__((ext_vector_type(8))) short bf16x8;
typedef __attribute__((ext_vector_type(4))) float f32x4;

__device__ __forceinline__ float fast_sigmoid(float x) {
    return 1.0f / (1.0f + __expf(-x));
}
__device__ __forceinline__ float fast_tanh(float x) {
    return 1.0f - 2.0f / (__expf(2.0f * x) + 1.0f);
}
__device__ __forceinline__ ushort f2bf(float v) {
    union { float f; unsigned u; } x; x.f = v;
    unsigned r = (x.u + 0x7FFFu + ((x.u >> 16) & 1u)) >> 16;
    return (ushort)r;
}
__device__ __forceinline__ float bf2f(ushort h) {
    union { unsigned u; float f; } x; x.u = ((unsigned)h) << 16;
    return x.f;
}

// ============================================================================
// pack_B: B (768 x 1280 logical) -> MFMA-fragment-ready bf16 (hi only).
// Rows: 0..255 = x (Wx), 256..511 = hL, 512..767 = hR.
// ctp = (nb*4+w)*5+g; col = g*256 + nb*64 + w*16 + c; g: 0=i 1=o 2=u 3=f0 4=f1.
// Frag slot (kt,ctp,lane l,j): B[kt*32+(l>>4)*8+j][c=(l&15)] at ((kt*80+ctp)*64+l)*8+j.
// ============================================================================
__global__ __launch_bounds__(256) void pack_B(const float* __restrict__ Wx,
                                              const float* __restrict__ Ui,
                                              const float* __restrict__ Uf,
                                              const float* __restrict__ Uo,
                                              const float* __restrict__ Uu,
                                              ushort* __restrict__ Bh)
{
    int tile = blockIdx.x * 4 + (threadIdx.x >> 6);   // 0..1919 = 24 kt x 80 ctp
    int l = threadIdx.x & 63;
    int kt = tile / 80;
    int ctp = tile % 80;
    int g = ctp % 5, w = (ctp / 5) & 3, nb = ctp / 20;
    int q = nb * 64 + w * 16 + (l & 15);
    size_t base = ((size_t)tile * 64 + l) * 8;
    #pragma unroll
    for (int j = 0; j < 8; j++) {
        int k = kt * 32 + ((l >> 4) * 8) + j;
        float v;
        if (k < 256) {
            // Wx gate order in reference: i,f,o,u
            int gc = (g == 0) ? q : (g == 1) ? (512 + q) : (g == 2) ? (768 + q) : (256 + q);
            v = Wx[(size_t)k * 1024 + gc];
        } else {
            int side = (k < 512) ? 0 : 1;            // hL / hR
            int e = k - 256 - side * 256;
            size_t off = (size_t)e * 256 + q;
            if (g == 0)      v = Ui[(size_t)side * 65536 + off];
            else if (g == 1) v = Uo[(size_t)side * 65536 + off];
            else if (g == 2) v = Uu[(size_t)side * 65536 + off];
            else {
                int j2 = g - 3;
                v = Uf[(size_t)(j2 * 2 + side) * 65536 + off];
            }
        }
        Bh[base + j] = f2bf(v);
    }
}

// ============================================================================
// pack_X: X = emb[tokens] for ALL nodes -> bf16 hi/lo [node][256] arrays.
// ============================================================================
__global__ __launch_bounds__(256) void pack_X(const int* __restrict__ tokens,
                                              const float* __restrict__ emb,
                                              ushort* __restrict__ XpH,
                                              ushort* __restrict__ XpL)
{
    int i = blockIdx.x * 256 + threadIdx.x;           // float4 index
    if (i >= NNODES * 64) return;
    int node = i >> 6, c4 = i & 63;
    int tok = tokens[node];
    float4 v = *(const float4*)(emb + (size_t)tok * 256 + c4 * 4);
    ushort4 hv, lv;
    hv.x = f2bf(v.x); lv.x = f2bf(v.x - bf2f(hv.x));
    hv.y = f2bf(v.y); lv.y = f2bf(v.y - bf2f(hv.y));
    hv.z = f2bf(v.z); lv.z = f2bf(v.z - bf2f(hv.z));
    hv.w = f2bf(v.w); lv.w = f2bf(v.w - bf2f(hv.w));
    *(ushort4*)(XpH + (size_t)node * 256 + c4 * 4) = hv;
    *(ushort4*)(XpL + (size_t)node * 256 + c4 * 4) = lv;
}

// ============================================================================
// tree_lds<MTC,LEAF>: big levels. A staged via pure 16B copies into
// XOR-swizzled LDS (slot kq^(row&7)); 2-term MFMA (Ah*B + Al*B); epilogue
// writes h (f32), c (f32) and packed h hi/lo for the parent level.
// ============================================================================
template <int MTC, bool LEAF>
__global__ __launch_bounds__(256, 2) void tree_lds(
    const ushort* __restrict__ XpH, const ushort* __restrict__ XpL,
    ushort* HpH, ushort* HpL,                 // read (children) + write (this level)
    const float* __restrict__ bias, const ushort* __restrict__ Bh,
    float* __restrict__ hbuf, float* __restrict__ cbuf,
    float* __restrict__ rootout, int lo, int m)
{
    constexpr int ROWS = MTC * 16;
    constexpr int KTOT = LEAF ? 256 : 768;
    constexpr int NG = LEAF ? 3 : 5;

    __shared__ __attribute__((aligned(16))) ushort AhsU[ROWS * 128];
    __shared__ __attribute__((aligned(16))) ushort AlsU[ROWS * 128];

    const int t = threadIdx.x;
    const int l = t & 63;
    const int w = t >> 6;
    const int base = blockIdx.x * ROWS;
    const int nb = blockIdx.y;

    f32x4 acc[MTC][NG];
    #pragma unroll
    for (int mt = 0; mt < MTC; mt++)
        #pragma unroll
        for (int g = 0; g < NG; g++)
            acc[mt][g] = (f32x4){0.f, 0.f, 0.f, 0.f};

    for (int kc = 0; kc < KTOT; kc += 128) {
        __syncthreads();
        // ---- stage chunk [ROWS][128] hi+lo: pure 16B copies, swizzled dst ----
        #pragma unroll
        for (int it = 0; it < MTC; it++) {
            int idx = it * 256 + t;            // ROWS*16 16B-quads
            int row = idx >> 4;
            int kq = idx & 15;
            int r2 = base + row; if (r2 >= m) r2 = m - 1;
            int node = lo + r2;
            const ushort *sH, *sL;
            if (LEAF || kc < 256) {
                size_t eoff = (size_t)node * 256 + (kc & 255) + kq * 8;
                sH = XpH + eoff; sL = XpL + eoff;
            } else {
                int child = 2 * node + ((kc < 512) ? 1 : 2);
                size_t eoff = (size_t)child * 256 + (kc & 255) + kq * 8;
                sH = HpH + eoff; sL = HpL + eoff;
            }
            int dst = row * 256 + ((kq ^ (row & 7)) << 4);
            *reinterpret_cast<bf16x8*>(reinterpret_cast<char*>(AhsU) + dst) =
                *reinterpret_cast<const bf16x8*>(sH);
            *reinterpret_cast<bf16x8*>(reinterpret_cast<char*>(AlsU) + dst) =
                *reinterpret_cast<const bf16x8*>(sL);
        }
        __syncthreads();

        // ---- 4 MFMA K-steps over this 128-K chunk ----
        #pragma unroll
        for (int ks = 0; ks < 4; ks++) {
            bf16x8 Ah[MTC], Al[MTC];
            #pragma unroll
            for (int mt = 0; mt < MTC; mt++) {
                int row = mt * 16 + (l & 15);
                int kqr = ks * 4 + (l >> 4);
                int off = row * 256 + ((kqr ^ (row & 7)) << 4);
                Ah[mt] = *reinterpret_cast<const bf16x8*>(reinterpret_cast<const char*>(AhsU) + off);
                Al[mt] = *reinterpret_cast<const bf16x8*>(reinterpret_cast<const char*>(AlsU) + off);
            }
            int kt = (kc >> 5) + ks;
            #pragma unroll
            for (int g = 0; g < NG; g++) {
                int ctp = (nb * 4 + w) * 5 + g;
                size_t boff = (((size_t)kt * 80 + ctp) * 64 + l) * 8;
                bf16x8 bh = *reinterpret_cast<const bf16x8*>(Bh + boff);
                #pragma unroll
                for (int mt = 0; mt < MTC; mt++) {
                    acc[mt][g] = __builtin_amdgcn_mfma_f32_16x16x32_bf16(Ah[mt], bh, acc[mt][g], 0, 0, 0);
                    acc[mt][g] = __builtin_amdgcn_mfma_f32_16x16x32_bf16(Al[mt], bh, acc[mt][g], 0, 0, 0);
                }
            }
        }
    }

    // ---- LSTM epilogue: C/D layout col=lane&15, row=(lane>>4)*4+reg ----
    int q = nb * 64 + w * 16 + (l & 15);
    float bi = bias[q], bff = bias[256 + q], bo = bias[512 + q], bu = bias[768 + q];
    #pragma unroll
    for (int mt = 0; mt < MTC; mt++) {
        #pragma unroll
        for (int r = 0; r < 4; r++) {
            int row = mt * 16 + (l >> 4) * 4 + r;
            if (base + row < m) {
                int node = lo + base + row;
                float iv = fast_sigmoid(acc[mt][0][r] + bi);
                float ov = fast_sigmoid(acc[mt][1][r] + bo);
                float uv = fast_tanh(acc[mt][2][r] + bu);
                float cn;
                if constexpr (LEAF) {
                    cn = iv * uv;
                } else {
                    float f0 = fast_sigmoid(acc[mt][3][r] + bff);
                    float f1 = fast_sigmoid(acc[mt][4][r] + bff);
                    float cl = cbuf[(size_t)(2 * node + 1) * 256 + q];
                    float cr = cbuf[(size_t)(2 * node + 2) * 256 + q];
                    cn = fmaf(iv, uv, fmaf(f0, cl, f1 * cr));
                }
                float hn = ov * fast_tanh(cn);
                hbuf[(size_t)node * 256 + q] = hn;
                cbuf[(size_t)node * 256 + q] = cn;
                ushort hh = f2bf(hn);
                HpH[(size_t)node * 256 + q] = hh;
                HpL[(size_t)node * 256 + q] = f2bf(hn - bf2f(hh));
                if constexpr (!LEAF) {
                    if (rootout != nullptr && node == 0) {
                        rootout[q] = hn;
                        rootout[256 + q] = cn;
                    }
                }
            }
        }
    }
}

// ============================================================================
// tree_direct: tail levels (m <= 2048). No LDS, no barriers — waves load
// A fragments straight from packed global arrays; fully pipelined.
// 16 nodes per block.x, q-block nb = blockIdx.y, wave w = q-subtile.
// ============================================================================
__global__ __launch_bounds__(256) void tree_direct(
    const ushort* __restrict__ XpH, const ushort* __restrict__ XpL,
    ushort* HpH, ushort* HpL,
    const float* __restrict__ bias, const ushort* __restrict__ Bh,
    float* __restrict__ hbuf, float* __restrict__ cbuf,
    float* __restrict__ rootout, int lo, int m)
{
    const int t = threadIdx.x;
    const int l = t & 63;
    const int w = t >> 6;
    const int base = blockIdx.x * 16;
    const int nb = blockIdx.y;

    int row = l & 15;
    int r2 = base + row; if (r2 >= m) r2 = m - 1;
    int node = lo + r2;
    int ksl = (l >> 4) * 8;

    f32x4 acc[5];
    #pragma unroll
    for (int g = 0; g < 5; g++) acc[g] = (f32x4){0.f, 0.f, 0.f, 0.f};

    const size_t xoff = (size_t)node * 256 + ksl;
    const size_t loff = (size_t)(2 * node + 1) * 256 + ksl;
    const size_t roff = (size_t)(2 * node + 2) * 256 + ksl;

    #pragma unroll
    for (int kt = 0; kt < 24; kt++) {
        const int k = kt * 32;
        const ushort *sH, *sL;
        if (kt < 8)       { sH = XpH + xoff + k;         sL = XpL + xoff + k; }
        else if (kt < 16) { sH = HpH + loff + (k - 256); sL = HpL + loff + (k - 256); }
        else              { sH = HpH + roff + (k - 512); sL = HpL + roff + (k - 512); }
        bf16x8 ah = *reinterpret_cast<const bf16x8*>(sH);
        bf16x8 al = *reinterpret_cast<const bf16x8*>(sL);
        #pragma unroll
        for (int g = 0; g < 5; g++) {
            size_t boff = (((size_t)kt * 80 + (nb * 4 + w) * 5 + g) * 64 + l) * 8;
            bf16x8 bh = *reinterpret_cast<const bf16x8*>(Bh + boff);
            acc[g] = __builtin_amdgcn_mfma_f32_16x16x32_bf16(ah, bh, acc[g], 0, 0, 0);
            acc[g] = __builtin_amdgcn_mfma_f32_16x16x32_bf16(al, bh, acc[g], 0, 0, 0);
        }
    }

    int q = nb * 64 + w * 16 + (l & 15);
    float bi = bias[q], bff = bias[256 + q], bo = bias[512 + q], bu = bias[768 + q];
    #pragma unroll
    for (int r = 0; r < 4; r++) {
        int rr = (l >> 4) * 4 + r;
        if (base + rr < m) {
            int nd = lo + base + rr;
            float iv = fast_sigmoid(acc[0][r] + bi);
            float ov = fast_sigmoid(acc[1][r] + bo);
            float uv = fast_tanh(acc[2][r] + bu);
            float f0 = fast_sigmoid(acc[3][r] + bff);
            float f1 = fast_sigmoid(acc[4][r] + bff);
            float cl = cbuf[(size_t)(2 * nd + 1) * 256 + q];
            float cr = cbuf[(size_t)(2 * nd + 2) * 256 + q];
            float cn = fmaf(iv, uv, fmaf(f0, cl, f1 * cr));
            float hn = ov * fast_tanh(cn);
            hbuf[(size_t)nd * 256 + q] = hn;
            cbuf[(size_t)nd * 256 + q] = cn;
            ushort hh = f2bf(hn);
            HpH[(size_t)nd * 256 + q] = hh;
            HpL[(size_t)nd * 256 + q] = f2bf(hn - bf2f(hh));
            if (rootout != nullptr && nd == 0) {
                rootout[q] = hn;
                rootout[256 + q] = cn;
            }
        }
    }
}

// ============================================================================
// Mid fallback (round-5 kernel, in-kernel cvt staging) — used if ws < 203 MB.
// ============================================================================
template <int MTC, bool LEAF>
__global__ __launch_bounds__(256, 2) void tree_level_mfma(
    const int* __restrict__ tokens, const float* __restrict__ emb,
    const float* __restrict__ bias,
    const ushort* __restrict__ Bh,
    float* __restrict__ hbuf, float* __restrict__ cbuf,
    float* __restrict__ rootout, int lo, int m)
{
    constexpr int ROWS = MTC * 16;
    constexpr int KTOT = LEAF ? 256 : 768;
    constexpr int NG = LEAF ? 3 : 5;

    __shared__ __attribute__((aligned(16))) ushort Ahs[ROWS * 128];
    __shared__ __attribute__((aligned(16))) ushort Als[ROWS * 128];

    const int t = threadIdx.x;
    const int l = t & 63;
    const int w = t >> 6;
    const int base = blockIdx.x * ROWS;
    const int nb = blockIdx.y;

    f32x4 acc[MTC][NG];
    #pragma unroll
    for (int mt = 0; mt < MTC; mt++)
        #pragma unroll
        for (int g = 0; g < NG; g++)
            acc[mt][g] = (f32x4){0.f, 0.f, 0.f, 0.f};

    for (int kc = 0; kc < KTOT; kc += 128) {
        __syncthreads();
        #pragma unroll
        for (int it = 0; it < MTC * 2; it++) {
            int f = it * 256 + t;
            int row = f >> 5;
            int c4 = f & 31;
            float4 v = make_float4(0.f, 0.f, 0.f, 0.f);
            if (base + row < m) {
                int node = lo + base + row;
                int rowoff = (kc & 255) + c4 * 4;
                if (LEAF || kc < 256) {
                    int tok = tokens[node];
                    v = *(const float4*)(emb + (size_t)tok * 256 + rowoff);
                } else {
                    int child = 2 * node + ((kc < 512) ? 1 : 2);
                    v = *(const float4*)(hbuf + (size_t)child * 256 + rowoff);
                }
            }
            ushort4 hv, lv;
            hv.x = f2bf(v.x); lv.x = f2bf(v.x - bf2f(hv.x));
            hv.y = f2bf(v.y); lv.y = f2bf(v.y - bf2f(hv.y));
            hv.z = f2bf(v.z); lv.z = f2bf(v.z - bf2f(hv.z));
            hv.w = f2bf(v.w); lv.w = f2bf(v.w - bf2f(hv.w));
            int byteoff = row * 256 + ((c4 * 8) ^ ((row & 7) << 4));
            *reinterpret_cast<ushort4*>(reinterpret_cast<char*>(Ahs) + byteoff) = hv;
            *reinterpret_cast<ushort4*>(reinterpret_cast<char*>(Als) + byteoff) = lv;
        }
        __syncthreads();

        #pragma unroll
        for (int ks = 0; ks < 4; ks++) {
            bf16x8 Ah[MTC], Al[MTC];
            #pragma unroll
            for (int mt = 0; mt < MTC; mt++) {
                int row = mt * 16 + (l & 15);
                int kb = (ks * 64 + (l >> 4) * 16) ^ ((row & 7) << 4);
                const char* p = reinterpret_cast<const char*>(Ahs) + row * 256 + kb;
                const char* pl = reinterpret_cast<const char*>(Als) + row * 256 + kb;
                Ah[mt] = *reinterpret_cast<const bf16x8*>(p);
                Al[mt] = *reinterpret_cast<const bf16x8*>(pl);
            }
            int kt = (kc >> 5) + ks;
            #pragma unroll
            for (int g = 0; g < NG; g++) {
                int ctp = (nb * 4 + w) * 5 + g;
                size_t boff = (((size_t)kt * 80 + ctp) * 64 + l) * 8;
                bf16x8 bh = *reinterpret_cast<const bf16x8*>(Bh + boff);
                #pragma unroll
                for (int mt = 0; mt < MTC; mt++) {
                    acc[mt][g] = __builtin_amdgcn_mfma_f32_16x16x32_bf16(Ah[mt], bh, acc[mt][g], 0, 0, 0);
                    acc[mt][g] = __builtin_amdgcn_mfma_f32_16x16x32_bf16(Al[mt], bh, acc[mt][g], 0, 0, 0);
                }
            }
        }
    }

    int q = nb * 64 + w * 16 + (l & 15);
    float bi = bias[q], bff = bias[256 + q], bo = bias[512 + q], bu = bias[768 + q];
    #pragma unroll
    for (int mt = 0; mt < MTC; mt++) {
        #pragma unroll
        for (int r = 0; r < 4; r++) {
            int row = mt * 16 + (l >> 4) * 4 + r;
            if (base + row < m) {
                int node = lo + base + row;
                float iv = fast_sigmoid(acc[mt][0][r] + bi);
                float ov = fast_sigmoid(acc[mt][1][r] + bo);
                float uv = fast_tanh(acc[mt][2][r] + bu);
                float cn;
                if constexpr (LEAF) {
                    cn = iv * uv;
                } else {
                    float f0 = fast_sigmoid(acc[mt][3][r] + bff);
                    float f1 = fast_sigmoid(acc[mt][4][r] + bff);
                    float cl = cbuf[(size_t)(2 * node + 1) * 256 + q];
                    float cr = cbuf[(size_t)(2 * node + 2) * 256 + q];
                    cn = fmaf(iv, uv, fmaf(f0, cl, f1 * cr));
                }
                float hn = ov * fast_tanh(cn);
                hbuf[(size_t)node * 256 + q] = hn;
                cbuf[(size_t)node * 256 + q] = cn;
                if constexpr (!LEAF) {
                    if (rootout != nullptr && node == 0) {
                        rootout[q] = hn;
                        rootout[256 + q] = cn;
                    }
                }
            }
        }
    }
}

// ============================================================================
// Last-resort fp32 path.
// ============================================================================
extern "C" __global__ void __launch_bounds__(256)
tree_level_kernel(const int* __restrict__ tokens,
                  const float* __restrict__ emb,
                  const float* __restrict__ Wx,
                  const float* __restrict__ bias,
                  const float* __restrict__ Ui,
                  const float* __restrict__ Uf,
                  const float* __restrict__ Uo,
                  const float* __restrict__ Uu,
                  float* __restrict__ hbuf,
                  float* __restrict__ cbuf,
                  float* __restrict__ rootout,
                  int lo, int m, int leaf)
{
    __shared__ float Xs[MT][E];
    __shared__ float HCs[MT][2 * H];
    const int t = threadIdx.x;
    const int base = blockIdx.x * MT;
    for (int i = t; i < MT * (E / 4); i += 256) {
        int r = i >> 6, c4 = i & 63;
        float4 v = make_float4(0.f, 0.f, 0.f, 0.f);
        if (base + r < m) {
            int node = lo + base + r;
            v = ((const float4*)(emb + (size_t)tokens[node] * E))[c4];
        }
        ((float4*)(Xs[r]))[c4] = v;
    }
    if (!leaf) {
        for (int i = t; i < MT * (2 * H / 4); i += 256) {
            int r = i >> 7, c4 = i & 127;
            float4 v = make_float4(0.f, 0.f, 0.f, 0.f);
            if (base + r < m) {
                int node = lo + base + r;
                int child = 2 * node + 1 + (c4 >> 6);
                v = ((const float4*)(hbuf + (size_t)child * H))[c4 & 63];
            }
            ((float4*)(HCs[r]))[c4] = v;
        }
    }
    __syncthreads();
    const float bi = bias[t], bf = bias[H + t], bo = bias[2 * H + t], bu = bias[3 * H + t];
    float axi[MT], axf[MT], axo[MT], axu[MT];
    #pragma unroll
    for (int r = 0; r < MT; r++) { axi[r] = bi; axf[r] = bf; axo[r] = bo; axu[r] = bu; }
    for (int e0 = 0; e0 < E; e0 += 4) {
        float4 xv[MT];
        #pragma unroll
        for (int r = 0; r < MT; r++) xv[r] = *(const float4*)&Xs[r][e0];
        #pragma unroll
        for (int q = 0; q < 4; q++) {
            const float* wrow = Wx + (size_t)(e0 + q) * (4 * H);
            float w0 = wrow[t], w1 = wrow[H + t], w2 = wrow[2 * H + t], w3 = wrow[3 * H + t];
            #pragma unroll
            for (int r = 0; r < MT; r++) {
                float xvq = ((const float*)&xv[r])[q];
                axi[r] = fmaf(xvq, w0, axi[r]);
                axf[r] = fmaf(xvq, w1, axf[r]);
                axo[r] = fmaf(xvq, w2, axo[r]);
                axu[r] = fmaf(xvq, w3, axu[r]);
            }
        }
    }
    float aci[MT], aco[MT], acu[MT], acf0[MT], acf1[MT];
    #pragma unroll
    for (int r = 0; r < MT; r++) { aci[r]=0.f; aco[r]=0.f; acu[r]=0.f; acf0[r]=0.f; acf1[r]=0.f; }
    if (!leaf) {
        for (int e0 = 0; e0 < 2 * H; e0 += 2) {
            float2 hv[MT];
            #pragma unroll
            for (int r = 0; r < MT; r++) hv[r] = *(const float2*)&HCs[r][e0];
            #pragma unroll
            for (int q = 0; q < 2; q++) {
                int e = e0 + q;
                float wi  = Ui[(size_t)e * H + t];
                float wo  = Uo[(size_t)e * H + t];
                float wu  = Uu[(size_t)e * H + t];
                float wf0 = Uf[(size_t)e * H + t];
                float wf1 = Uf[2 * H * H + (size_t)e * H + t];
                #pragma unroll
                for (int r = 0; r < MT; r++) {
                    float hvq = ((const float*)&hv[r])[q];
                    aci[r]  = fmaf(hvq, wi,  aci[r]);
                    aco[r]  = fmaf(hvq, wo,  aco[r]);
                    acu[r]  = fmaf(hvq, wu,  acu[r]);
                    acf0[r] = fmaf(hvq, wf0, acf0[r]);
                    acf1[r] = fmaf(hvq, wf1, acf1[r]);
                }
            }
        }
    }
    #pragma unroll
    for (int r = 0; r < MT; r++) {
        if (base + r < m) {
            int node = lo + base + r;
            float iv = fast_sigmoid(axi[r] + aci[r]);
            float ov = fast_sigmoid(axo[r] + aco[r]);
            float uv = fast_tanh(axu[r] + acu[r]);
            float cn;
            if (leaf) cn = iv * uv;
            else {
                float f0 = fast_sigmoid(axf[r] + acf0[r]);
                float f1 = fast_sigmoid(axf[r] + acf1[r]);
                float cl = cbuf[(size_t)(2 * node + 1) * H + t];
                float cr = cbuf[(size_t)(2 * node + 2) * H + t];
                cn = fmaf(iv, uv, fmaf(f0, cl, f1 * cr));
            }
            float hn = ov * fast_tanh(cn);
            hbuf[(size_t)node * H + t] = hn;
            cbuf[(size_t)node * H + t] = cn;
            if (rootout != nullptr && node == 0) { rootout[t] = hn; rootout[H + t] = cn; }
        }
    }
}

extern "C" void kernel_launch(void* const* d_in, const int* in_sizes, int n_in,
                              void* d_out, int out_size, void* d_ws, size_t ws_size,
                              hipStream_t stream)
{
    const int*   tokens = (const int*)d_in[0];
    const float* emb    = (const float*)d_in[1];
    const float* Wx     = (const float*)d_in[2];
    const float* bias   = (const float*)d_in[3];
    const float* Ui     = (const float*)d_in[4];
    const float* Uf     = (const float*)d_in[5];
    const float* Uo     = (const float*)d_in[6];
    const float* Uu     = (const float*)d_in[7];

    float* out = (float*)d_out;
    float* hbuf = out;                              // annotations [N, H]
    float* rootout = out + (size_t)NNODES * H;      // h[0], c[0]

    const size_t cbytes  = (size_t)NNODES * H * sizeof(float);   // 67,107,840
    const size_t bhBytes = (size_t)768 * 1280 * sizeof(ushort);  //  1,966,080
    const size_t packB   = (size_t)NNODES * 256 * sizeof(ushort);// 33,553,920 each
    const size_t need_full = cbytes + bhBytes + 4 * packB;       // ~203.3 MB
    const size_t need_mid  = cbytes + bhBytes;                   // ~69 MB

    float* cbuf = (float*)d_ws;

    if (ws_size >= need_full) {
        ushort* Bh  = (ushort*)((char*)d_ws + cbytes);
        ushort* XpH = (ushort*)((char*)d_ws + cbytes + bhBytes);
        ushort* XpL = XpH + (size_t)NNODES * 256;
        ushort* HpH = XpL + (size_t)NNODES * 256;
        ushort* HpL = HpH + (size_t)NNODES * 256;

        pack_B<<<480, 256, 0, stream>>>(Wx, Ui, Uf, Uo, Uu, Bh);
        pack_X<<<16384, 256, 0, stream>>>(tokens, emb, XpH, XpL);

        for (int d = DEPTH - 1; d >= 0; d--) {
            int m = 1 << d;
            int lo = m - 1;
            float* ro = (d == 0) ? rootout : nullptr;
            if (d == DEPTH - 1) {
                tree_lds<4, true><<<dim3(m / 64, 4), 256, 0, stream>>>(
                    XpH, XpL, HpH, HpL, bias, Bh, hbuf, cbuf, nullptr, lo, m);
            } else if (m >= 8192) {
                tree_lds<4, false><<<dim3(m / 64, 4), 256, 0, stream>>>(
                    XpH, XpL, HpH, HpL, bias, Bh, hbuf, cbuf, ro, lo, m);
            } else if (m >= 4096) {
                tree_lds<2, false><<<dim3(m / 32, 4), 256, 0, stream>>>(
                    XpH, XpL, HpH, HpL, bias, Bh, hbuf, cbuf, ro, lo, m);
            } else {
                int gx = (m + 15) / 16;
                tree_direct<<<dim3(gx, 4), 256, 0, stream>>>(
                    XpH, XpL, HpH, HpL, bias, Bh, hbuf, cbuf, ro, lo, m);
            }
        }
    } else if (ws_size >= need_mid) {
        ushort* Bh = (ushort*)((char*)d_ws + cbytes);
        pack_B<<<480, 256, 0, stream>>>(Wx, Ui, Uf, Uo, Uu, Bh);
        for (int d = DEPTH - 1; d >= 0; d--) {
            int m = 1 << d;
            int lo = m - 1;
            float* ro = (d == 0) ? rootout : nullptr;
            if (d == DEPTH - 1) {
                tree_level_mfma<4, true><<<dim3(m / 64, 4), 256, 0, stream>>>(
                    tokens, emb, bias, Bh, hbuf, cbuf, nullptr, lo, m);
            } else if (m >= 8192) {
                tree_level_mfma<4, false><<<dim3(m / 64, 4), 256, 0, stream>>>(
                    tokens, emb, bias, Bh, hbuf, cbuf, ro, lo, m);
            } else if (m >= 4096) {
                tree_level_mfma<2, false><<<dim3(m / 32, 4), 256, 0, stream>>>(
                    tokens, emb, bias, Bh, hbuf, cbuf, ro, lo, m);
            } else {
                int gx = (m + 15) / 16;
                tree_level_mfma<1, false><<<dim3(gx, 4), 256, 0, stream>>>(
                    tokens, emb, bias, Bh, hbuf, cbuf, ro, lo, m);
            }
        }
    } else {
        for (int d = DEPTH - 1; d >= 0; d--) {
            int m = 1 << d;
            int lo = m - 1;
            int grid = (m + MT - 1) / MT;
            tree_level_kernel<<<grid, 256, 0, stream>>>(
                tokens, emb, Wx, bias, Ui, Uf, Uo, Uu,
                hbuf, cbuf, (d == 0) ? rootout : nullptr,
                lo, m, (d == DEPTH - 1) ? 1 : 0);
        }
    }
}

// Round 10
// 493.603 us; speedup vs baseline: 4.7990x; 1.0913x over previous
//
#include <hip/hip_runtime.h>

#define E 256
#define H 256
#define NNODES 65535
#define DEPTH 16
#define MT 8   // fallback fp32 kernel

typedef __attribute__((ext_vector_type(8))) short bf16x8;
typedef __attribute__((ext_vector_type(4))) float f32x4;

__device__ __forceinline__ float fast_sigmoid(float x) {
    return 1.0f / (1.0f + __expf(-x));
}
__device__ __forceinline__ float fast_tanh(float x) {
    return 1.0f - 2.0f / (__expf(2.0f * x) + 1.0f);
}
__device__ __forceinline__ ushort f2bf(float v) {
    union { float f; unsigned u; } x; x.f = v;
    unsigned r = (x.u + 0x7FFFu + ((x.u >> 16) & 1u)) >> 16;
    return (ushort)r;
}
__device__ __forceinline__ float bf2f(ushort h) {
    union { unsigned u; float f; } x; x.u = ((unsigned)h) << 16;
    return x.f;
}

// ============================================================================
// pack_B: logical B (768 x 1280) -> frag-linear bf16 Bp[kt(24)][ct(80)][64][8].
// Logical col c = g*256 + q  (g: 0=i 1=o 2=u 3=f0 4=f1);  ct = g*16 + q/16.
// Frag (kt, ct), lane l, j: value B[kt*32 + (l>>4)*8 + j][ct*16 + (l&15)].
// Rows k: 0..255 = x (Wx), 256..511 = hL, 512..767 = hR.
// ============================================================================
__global__ __launch_bounds__(256) void pack_B(const float* __restrict__ Wx,
                                              const float* __restrict__ Ui,
                                              const float* __restrict__ Uf,
                                              const float* __restrict__ Uo,
                                              const float* __restrict__ Uu,
                                              ushort* __restrict__ Bp)
{
    int tile = blockIdx.x * 4 + (threadIdx.x >> 6);   // 0..1919 = kt*80 + ct
    int l = threadIdx.x & 63;
    int kt = tile / 80;
    int ct = tile % 80;
    int g = ct >> 4;
    int q = (ct & 15) * 16 + (l & 15);
    size_t base = ((size_t)tile * 64 + l) * 8;
    #pragma unroll
    for (int j = 0; j < 8; j++) {
        int k = kt * 32 + ((l >> 4) * 8) + j;
        float v;
        if (k < 256) {
            // Wx gate order in reference: i,f,o,u
            int gc = (g == 0) ? q : (g == 1) ? (512 + q) : (g == 2) ? (768 + q) : (256 + q);
            v = Wx[(size_t)k * 1024 + gc];
        } else {
            int side = (k < 512) ? 0 : 1;            // hL / hR
            int e = k - 256 - side * 256;
            size_t off = (size_t)e * 256 + q;
            if (g == 0)      v = Ui[(size_t)side * 65536 + off];
            else if (g == 1) v = Uo[(size_t)side * 65536 + off];
            else if (g == 2) v = Uu[(size_t)side * 65536 + off];
            else {
                int j2 = g - 3;                      // forget gate of child j2
                v = Uf[(size_t)(j2 * 2 + side) * 65536 + off];
            }
        }
        Bp[base + j] = f2bf(v);
    }
}

// ============================================================================
// pack_X: X = emb[tokens] for ALL nodes -> bf16 (hi only) [node][256].
// ============================================================================
__global__ __launch_bounds__(256) void pack_X(const int* __restrict__ tokens,
                                              const float* __restrict__ emb,
                                              ushort* __restrict__ Xp)
{
    int i = blockIdx.x * 256 + threadIdx.x;           // float4 index
    if (i >= NNODES * 64) return;
    int node = i >> 6, c4 = i & 63;
    int tok = tokens[node];
    float4 v = *(const float4*)(emb + (size_t)tok * 256 + c4 * 4);
    ushort4 hv;
    hv.x = f2bf(v.x); hv.y = f2bf(v.y); hv.z = f2bf(v.z); hv.w = f2bf(v.w);
    *(ushort4*)(Xp + (size_t)node * 256 + c4 * 4) = hv;
}

// ============================================================================
// tree_gemm<ROWS,NG>: one tree level (NG=5 internal K=768, NG=3 leaf K=256).
// Block: 512 threads (8 waves), ROWS rows x (NG gates x 64 q) cols; BK=32.
// Wave (rh,ch): rh = w>>2 rowhalf, ch = w&3 q-16-subtile; tile = ROWS/2 x NG*16.
// A: LDS row-major [row][32K], source-preswizzled quads (linear ds_write,
//    2-way-free ds_read).  B: LDS frag-linear (fully contiguous both sides).
// ============================================================================
template <int ROWS, int NG>
__global__ __launch_bounds__(512) void tree_gemm(
    const ushort* __restrict__ Xp, ushort* Hp,
    const float* __restrict__ bias, const ushort* __restrict__ Bp,
    float* __restrict__ hbuf, float* __restrict__ cbuf,
    int lo, int m)
{
    constexpr int KTOT = (NG == 3) ? 256 : 768;
    constexpr int MTC = ROWS / 32;                 // m-frags per wave
    constexpr int ALINES = ROWS * 4;               // 16B lines of A per chunk
    constexpr int BLINES = NG * 4 * 64;            // 16B lines of B per chunk

    __shared__ __attribute__((aligned(16))) ushort A_lds[ROWS * 32];
    __shared__ __attribute__((aligned(16))) ushort B_lds[NG * 4 * 64 * 8];

    const int t = threadIdx.x;
    const int l = t & 63;
    const int w = t >> 6;
    const int rh = w >> 2;
    const int ch = w & 3;
    const int base = blockIdx.x * ROWS;
    const int nb = blockIdx.y;
    const int rowbase = rh * (ROWS / 2);

    f32x4 acc[MTC][NG];
    #pragma unroll
    for (int mt = 0; mt < MTC; mt++)
        #pragma unroll
        for (int g = 0; g < NG; g++)
            acc[mt][g] = (f32x4){0.f, 0.f, 0.f, 0.f};

    for (int kc = 0; kc < KTOT; kc += 32) {
        __syncthreads();   // previous chunk's readers done
        // ---- stage A [ROWS][32K]: linear LDS write, pre-swizzled global src ----
        #pragma unroll
        for (int i = 0; i < (ALINES + 511) / 512; i++) {
            int line = i * 512 + t;                // ROWS*4 lines of 16B
            if (ALINES % 512 == 0 || line < ALINES) {
                int row = line >> 2;
                int slot = line & 3;
                int kq = slot ^ (row & 3);         // involution: read undoes it
                int r2 = base + row; if (r2 >= m) r2 = m - 1;
                int node = lo + r2;
                const ushort* src;
                if (NG == 3 || kc < 256) {
                    src = Xp + (size_t)node * 256 + (kc & 255) + kq * 8;
                } else {
                    int child = 2 * node + ((kc < 512) ? 1 : 2);
                    src = Hp + (size_t)child * 256 + ((kc - 256) & 255) + kq * 8;
                }
                *reinterpret_cast<bf16x8*>(reinterpret_cast<char*>(A_lds) + line * 16) =
                    *reinterpret_cast<const bf16x8*>(src);
            }
        }
        // ---- stage B: frag-linear copies (contiguous 16B lines) ----
        int kt = kc >> 5;
        #pragma unroll
        for (int i = 0; i < (BLINES + 511) / 512; i++) {
            int line = i * 512 + t;
            if (BLINES % 512 == 0 || line < BLINES) {
                int lane = line & 63;
                int frag = line >> 6;              // g*4 + j
                int g = frag >> 2, j = frag & 3;
                int ct = g * 16 + nb * 4 + j;
                size_t s = (((size_t)kt * 80 + ct) * 64 + lane) * 8;
                reinterpret_cast<bf16x8*>(B_lds)[line] =
                    *reinterpret_cast<const bf16x8*>(Bp + s);
            }
        }
        __syncthreads();

        // ---- one K=32 MFMA step ----
        bf16x8 Bf[NG];
        #pragma unroll
        for (int g = 0; g < NG; g++)
            Bf[g] = reinterpret_cast<const bf16x8*>(B_lds)[(g * 4 + ch) * 64 + l];
        int slotbyte = (((l >> 4) ^ (l & 3)) << 4);
        #pragma unroll
        for (int mt = 0; mt < MTC; mt++) {
            int row = rowbase + mt * 16 + (l & 15);
            bf16x8 Af = *reinterpret_cast<const bf16x8*>(
                reinterpret_cast<const char*>(A_lds) + row * 64 + slotbyte);
            #pragma unroll
            for (int g = 0; g < NG; g++)
                acc[mt][g] = __builtin_amdgcn_mfma_f32_16x16x32_bf16(Af, Bf[g], acc[mt][g], 0, 0, 0);
        }
    }

    // ---- LSTM epilogue: C/D col=lane&15, row=(lane>>4)*4+reg ----
    int q = nb * 64 + ch * 16 + (l & 15);
    float bi = bias[q], bff = bias[256 + q], bo = bias[512 + q], bu = bias[768 + q];
    #pragma unroll
    for (int mt = 0; mt < MTC; mt++) {
        #pragma unroll
        for (int r = 0; r < 4; r++) {
            int row = rowbase + mt * 16 + (l >> 4) * 4 + r;
            if (base + row < m) {
                int node = lo + base + row;
                float iv = fast_sigmoid(acc[mt][0][r] + bi);
                float ov = fast_sigmoid(acc[mt][1][r] + bo);
                float uv = fast_tanh(acc[mt][2][r] + bu);
                float cn;
                if constexpr (NG == 3) {
                    cn = iv * uv;
                } else {
                    float f0 = fast_sigmoid(acc[mt][3][r] + bff);
                    float f1 = fast_sigmoid(acc[mt][4][r] + bff);
                    float cl = cbuf[(size_t)(2 * node + 1) * 256 + q];
                    float cr = cbuf[(size_t)(2 * node + 2) * 256 + q];
                    cn = fmaf(iv, uv, fmaf(f0, cl, f1 * cr));
                }
                float hn = ov * fast_tanh(cn);
                hbuf[(size_t)node * 256 + q] = hn;
                cbuf[(size_t)node * 256 + q] = cn;
                Hp[(size_t)node * 256 + q] = f2bf(hn);
            }
        }
    }
}

// ============================================================================
// tree_direct: tail levels (m <= 2048). No LDS/barriers; A,B frags straight
// from packed global (L2-resident). 16 nodes/block.x, nb = blockIdx.y.
// ============================================================================
__global__ __launch_bounds__(256) void tree_direct(
    const ushort* __restrict__ Xp, ushort* Hp,
    const float* __restrict__ bias, const ushort* __restrict__ Bp,
    float* __restrict__ hbuf, float* __restrict__ cbuf,
    float* __restrict__ rootout, int lo, int m)
{
    const int t = threadIdx.x;
    const int l = t & 63;
    const int w = t >> 6;
    const int base = blockIdx.x * 16;
    const int nb = blockIdx.y;

    int row = l & 15;
    int r2 = base + row; if (r2 >= m) r2 = m - 1;
    int node = lo + r2;
    int ksl = (l >> 4) * 8;

    f32x4 acc[5];
    #pragma unroll
    for (int g = 0; g < 5; g++) acc[g] = (f32x4){0.f, 0.f, 0.f, 0.f};

    const size_t xoff = (size_t)node * 256 + ksl;
    const size_t loff = (size_t)(2 * node + 1) * 256 + ksl;
    const size_t roff = (size_t)(2 * node + 2) * 256 + ksl;

    #pragma unroll
    for (int kt = 0; kt < 24; kt++) {
        const int k = kt * 32;
        const ushort* sH;
        if (kt < 8)       sH = Xp + xoff + k;
        else if (kt < 16) sH = Hp + loff + (k - 256);
        else              sH = Hp + roff + (k - 512);
        bf16x8 ah = *reinterpret_cast<const bf16x8*>(sH);
        #pragma unroll
        for (int g = 0; g < 5; g++) {
            size_t boff = (((size_t)kt * 80 + g * 16 + nb * 4 + w) * 64 + l) * 8;
            bf16x8 bh = *reinterpret_cast<const bf16x8*>(Bp + boff);
            acc[g] = __builtin_amdgcn_mfma_f32_16x16x32_bf16(ah, bh, acc[g], 0, 0, 0);
        }
    }

    int q = nb * 64 + w * 16 + (l & 15);
    float bi = bias[q], bff = bias[256 + q], bo = bias[512 + q], bu = bias[768 + q];
    #pragma unroll
    for (int r = 0; r < 4; r++) {
        int rr = (l >> 4) * 4 + r;
        if (base + rr < m) {
            int nd = lo + base + rr;
            float iv = fast_sigmoid(acc[0][r] + bi);
            float ov = fast_sigmoid(acc[1][r] + bo);
            float uv = fast_tanh(acc[2][r] + bu);
            float f0 = fast_sigmoid(acc[3][r] + bff);
            float f1 = fast_sigmoid(acc[4][r] + bff);
            float cl = cbuf[(size_t)(2 * nd + 1) * 256 + q];
            float cr = cbuf[(size_t)(2 * nd + 2) * 256 + q];
            float cn = fmaf(iv, uv, fmaf(f0, cl, f1 * cr));
            float hn = ov * fast_tanh(cn);
            hbuf[(size_t)nd * 256 + q] = hn;
            cbuf[(size_t)nd * 256 + q] = cn;
            Hp[(size_t)nd * 256 + q] = f2bf(hn);
            if (rootout != nullptr && nd == 0) {
                rootout[q] = hn;
                rootout[256 + q] = cn;
            }
        }
    }
}

// ============================================================================
// Last-resort fp32 path (known-correct round-2 kernel).
// ============================================================================
extern "C" __global__ void __launch_bounds__(256)
tree_level_kernel(const int* __restrict__ tokens,
                  const float* __restrict__ emb,
                  const float* __restrict__ Wx,
                  const float* __restrict__ bias,
                  const float* __restrict__ Ui,
                  const float* __restrict__ Uf,
                  const float* __restrict__ Uo,
                  const float* __restrict__ Uu,
                  float* __restrict__ hbuf,
                  float* __restrict__ cbuf,
                  float* __restrict__ rootout,
                  int lo, int m, int leaf)
{
    __shared__ float Xs[MT][E];
    __shared__ float HCs[MT][2 * H];
    const int t = threadIdx.x;
    const int base = blockIdx.x * MT;
    for (int i = t; i < MT * (E / 4); i += 256) {
        int r = i >> 6, c4 = i & 63;
        float4 v = make_float4(0.f, 0.f, 0.f, 0.f);
        if (base + r < m) {
            int node = lo + base + r;
            v = ((const float4*)(emb + (size_t)tokens[node] * E))[c4];
        }
        ((float4*)(Xs[r]))[c4] = v;
    }
    if (!leaf) {
        for (int i = t; i < MT * (2 * H / 4); i += 256) {
            int r = i >> 7, c4 = i & 127;
            float4 v = make_float4(0.f, 0.f, 0.f, 0.f);
            if (base + r < m) {
                int node = lo + base + r;
                int child = 2 * node + 1 + (c4 >> 6);
                v = ((const float4*)(hbuf + (size_t)child * H))[c4 & 63];
            }
            ((float4*)(HCs[r]))[c4] = v;
        }
    }
    __syncthreads();
    const float bi = bias[t], bf = bias[H + t], bo = bias[2 * H + t], bu = bias[3 * H + t];
    float axi[MT], axf[MT], axo[MT], axu[MT];
    #pragma unroll
    for (int r = 0; r < MT; r++) { axi[r] = bi; axf[r] = bf; axo[r] = bo; axu[r] = bu; }
    for (int e0 = 0; e0 < E; e0 += 4) {
        float4 xv[MT];
        #pragma unroll
        for (int r = 0; r < MT; r++) xv[r] = *(const float4*)&Xs[r][e0];
        #pragma unroll
        for (int q = 0; q < 4; q++) {
            const float* wrow = Wx + (size_t)(e0 + q) * (4 * H);
            float w0 = wrow[t], w1 = wrow[H + t], w2 = wrow[2 * H + t], w3 = wrow[3 * H + t];
            #pragma unroll
            for (int r = 0; r < MT; r++) {
                float xvq = ((const float*)&xv[r])[q];
                axi[r] = fmaf(xvq, w0, axi[r]);
                axf[r] = fmaf(xvq, w1, axf[r]);
                axo[r] = fmaf(xvq, w2, axo[r]);
                axu[r] = fmaf(xvq, w3, axu[r]);
            }
        }
    }
    float aci[MT], aco[MT], acu[MT], acf0[MT], acf1[MT];
    #pragma unroll
    for (int r = 0; r < MT; r++) { aci[r]=0.f; aco[r]=0.f; acu[r]=0.f; acf0[r]=0.f; acf1[r]=0.f; }
    if (!leaf) {
        for (int e0 = 0; e0 < 2 * H; e0 += 2) {
            float2 hv[MT];
            #pragma unroll
            for (int r = 0; r < MT; r++) hv[r] = *(const float2*)&HCs[r][e0];
            #pragma unroll
            for (int q = 0; q < 2; q++) {
                int e = e0 + q;
                float wi  = Ui[(size_t)e * H + t];
                float wo  = Uo[(size_t)e * H + t];
                float wu  = Uu[(size_t)e * H + t];
                float wf0 = Uf[(size_t)e * H + t];
                float wf1 = Uf[2 * H * H + (size_t)e * H + t];
                #pragma unroll
                for (int r = 0; r < MT; r++) {
                    float hvq = ((const float*)&hv[r])[q];
                    aci[r]  = fmaf(hvq, wi,  aci[r]);
                    aco[r]  = fmaf(hvq, wo,  aco[r]);
                    acu[r]  = fmaf(hvq, wu,  acu[r]);
                    acf0[r] = fmaf(hvq, wf0, acf0[r]);
                    acf1[r] = fmaf(hvq, wf1, acf1[r]);
                }
            }
        }
    }
    #pragma unroll
    for (int r = 0; r < MT; r++) {
        if (base + r < m) {
            int node = lo + base + r;
            float iv = fast_sigmoid(axi[r] + aci[r]);
            float ov = fast_sigmoid(axo[r] + aco[r]);
            float uv = fast_tanh(axu[r] + acu[r]);
            float cn;
            if (leaf) cn = iv * uv;
            else {
                float f0 = fast_sigmoid(axf[r] + acf0[r]);
                float f1 = fast_sigmoid(axf[r] + acf1[r]);
                float cl = cbuf[(size_t)(2 * node + 1) * H + t];
                float cr = cbuf[(size_t)(2 * node + 2) * H + t];
                cn = fmaf(iv, uv, fmaf(f0, cl, f1 * cr));
            }
            float hn = ov * fast_tanh(cn);
            hbuf[(size_t)node * H + t] = hn;
            cbuf[(size_t)node * H + t] = cn;
            if (rootout != nullptr && node == 0) { rootout[t] = hn; rootout[H + t] = cn; }
        }
    }
}

extern "C" void kernel_launch(void* const* d_in, const int* in_sizes, int n_in,
                              void* d_out, int out_size, void* d_ws, size_t ws_size,
                              hipStream_t stream)
{
    const int*   tokens = (const int*)d_in[0];
    const float* emb    = (const float*)d_in[1];
    const float* Wx     = (const float*)d_in[2];
    const float* bias   = (const float*)d_in[3];
    const float* Ui     = (const float*)d_in[4];
    const float* Uf     = (const float*)d_in[5];
    const float* Uo     = (const float*)d_in[6];
    const float* Uu     = (const float*)d_in[7];

    float* out = (float*)d_out;
    float* hbuf = out;                              // annotations [N, H]
    float* rootout = out + (size_t)NNODES * H;      // h[0], c[0]

    const size_t cbytes  = (size_t)NNODES * H * sizeof(float);    // 67,107,840
    const size_t bpBytes = (size_t)24 * 80 * 64 * 8 * sizeof(ushort); // 1,966,080
    const size_t packB   = (size_t)NNODES * 256 * sizeof(ushort); // 33,553,920
    const size_t need    = cbytes + bpBytes + 2 * packB;          // ~136.2 MB

    float* cbuf = (float*)d_ws;

    if (ws_size >= need) {
        ushort* Bp = (ushort*)((char*)d_ws + cbytes);
        ushort* Xp = (ushort*)((char*)d_ws + cbytes + bpBytes);
        ushort* Hp = Xp + (size_t)NNODES * 256;

        pack_B<<<480, 256, 0, stream>>>(Wx, Ui, Uf, Uo, Uu, Bp);
        pack_X<<<16384, 256, 0, stream>>>(tokens, emb, Xp);

        for (int d = DEPTH - 1; d >= 0; d--) {
            int m = 1 << d;
            int lo = m - 1;
            if (d == DEPTH - 1) {
                tree_gemm<256, 3><<<dim3(m / 256, 4), 512, 0, stream>>>(
                    Xp, Hp, bias, Bp, hbuf, cbuf, lo, m);
            } else if (m >= 16384) {
                tree_gemm<256, 5><<<dim3(m / 256, 4), 512, 0, stream>>>(
                    Xp, Hp, bias, Bp, hbuf, cbuf, lo, m);
            } else if (m >= 8192) {
                tree_gemm<128, 5><<<dim3(m / 128, 4), 512, 0, stream>>>(
                    Xp, Hp, bias, Bp, hbuf, cbuf, lo, m);
            } else if (m >= 4096) {
                tree_gemm<64, 5><<<dim3(m / 64, 4), 512, 0, stream>>>(
                    Xp, Hp, bias, Bp, hbuf, cbuf, lo, m);
            } else {
                int gx = (m + 15) / 16;
                tree_direct<<<dim3(gx, 4), 256, 0, stream>>>(
                    Xp, Hp, bias, Bp, hbuf, cbuf,
                    (d == 0) ? rootout : nullptr, lo, m);
            }
        }
    } else {
        for (int d = DEPTH - 1; d >= 0; d--) {
            int m = 1 << d;
            int lo = m - 1;
            int grid = (m + MT - 1) / MT;
            tree_level_kernel<<<grid, 256, 0, stream>>>(
                tokens, emb, Wx, bias, Ui, Uf, Uo, Uu,
                hbuf, cbuf, (d == 0) ? rootout : nullptr,
                lo, m, (d == DEPTH - 1) ? 1 : 0);
        }
    }
}